// Round 5
// baseline (142.551 us; speedup 1.0000x reference)
//
#include <hip/hip_runtime.h>
#include <hip/hip_bf16.h>
#include <stdint.h>

// Problem constants (B=1)
#define NN   256     // MSA depth (contraction K of GEMM1)
#define LL   192
#define MDIM 6144    // L*J
#define D2   1024    // J*J
#define FF   128     // n_feat_out

typedef __bf16 bf16x8 __attribute__((ext_vector_type(8)));
typedef float  f32x4  __attribute__((ext_vector_type(4)));

#define MFMA16(a, b, c) __builtin_amdgcn_mfma_f32_16x16x32_bf16(a, b, c, 0, 0, 0)

__device__ __forceinline__ void gload_lds16(const void* g, void* l) {
  __builtin_amdgcn_global_load_lds(
      (__attribute__((address_space(1))) void*)(g),
      (__attribute__((address_space(3))) void*)(l),
      16, 0, 0);
}

static __device__ __forceinline__ unsigned short bf16_bits(float v) {
  __bf16 h = (__bf16)v;
  return __builtin_bit_cast(unsigned short, h);
}

// ---------------------------------------------------------------------------
// Unified prep (one launch):
//  blocks [0,1536):    transpose x_down  [256][6144] f32 -> At [6144][256] bf16
//  blocks [1536,3072): transpose x_down_w            -> Bt
//  blocks [3072,3200): WB[fragment-linear] = bf16(a2*W), S = colsum, T = b2@W+b
// ---------------------------------------------------------------------------
__global__ __launch_bounds__(256)
void prep_all(const float* __restrict__ x1, const float* __restrict__ x2,
              const float* __restrict__ W, const float* __restrict__ a2,
              const float* __restrict__ b2, const float* __restrict__ bias,
              __bf16* __restrict__ At, __bf16* __restrict__ Bt,
              __bf16* __restrict__ WB, float* __restrict__ S,
              float* __restrict__ T) {
  __shared__ float tile[32][33];
  const int b = blockIdx.x;
  const int t = threadIdx.x;
  if (b < 3072) {
    const float* src = (b < 1536) ? x1 : x2;
    __bf16* dst = (b < 1536) ? At : Bt;
    const int bb = (b < 1536) ? b : b - 1536;
    const int m0 = (bb % 192) * 32;
    const int k0 = (bb / 192) * 32;
    {
      const int kr = t >> 3, mc = (t & 7) * 4;
      const float4 v = *(const float4*)&src[(size_t)(k0 + kr) * MDIM + m0 + mc];
      tile[kr][mc + 0] = v.x;
      tile[kr][mc + 1] = v.y;
      tile[kr][mc + 2] = v.z;
      tile[kr][mc + 3] = v.w;
    }
    __syncthreads();
    {
      const int mr = t >> 3, kc = (t & 7) * 4;
      ushort4 u;
      u.x = bf16_bits(tile[kc + 0][mr]);
      u.y = bf16_bits(tile[kc + 1][mr]);
      u.z = bf16_bits(tile[kc + 2][mr]);
      u.w = bf16_bits(tile[kc + 3][mr]);
      *(ushort4*)&dst[(size_t)(m0 + mr) * NN + k0 + kc] = u;
    }
  } else {
    const int f = b - 3072;
    float s = 0.f, tt = 0.f;
#pragma unroll
    for (int it = 0; it < 4; ++it) {
      const int k = t + it * 256;
      const float wv = W[(size_t)k * FF + f];
      const __bf16 wa = (__bf16)(a2[k] * wv);
      WB[(size_t)(k >> 5) * 4096 + f * 32 + ((k >> 3) & 3) * 8 + (k & 7)] = wa;
      s += (float)wa;
      tt += b2[k] * wv;
    }
#pragma unroll
    for (int off = 32; off; off >>= 1) {
      s += __shfl_xor(s, off);
      tt += __shfl_xor(tt, off);
    }
    const int wv_ = t >> 6, ln = t & 63;
    if (ln == 0) { tile[0][wv_] = s; tile[1][wv_] = tt; }
    __syncthreads();
    if (t == 0) {
      S[f] = tile[0][0] + tile[0][1] + tile[0][2] + tile[0][3];
      T[f] = tile[1][0] + tile[1][1] + tile[1][2] + tile[1][3] + bias[f];
    }
  }
}

// ---------------------------------------------------------------------------
// Fused kernel R5: XCD-banded 128x128 tiles; GEMM1 with BK=32 double-buffered
// LDS pipeline (stage chunk k+1 before computing chunk k -> each barrier's
// vmcnt drain targets loads issued a full chunk earlier); per-32x32-block LN
// stats; packed-b32 swizzled Xs scatter (Xs aliases the staging buffers);
// GEMM2 (1024->128, WB frag-linear, depth-4 register pipeline); affine
// epilogue. out = rstd*(x@Wa - mean*S) + T.
// No min-wave __launch_bounds__ cap (spill tripwire: WRITE_SIZE == 18432 KB).
// ---------------------------------------------------------------------------
__global__ __launch_bounds__(256)
void fused5(const __bf16* __restrict__ At, const __bf16* __restrict__ Bt,
            const __bf16* __restrict__ WB, const float* __restrict__ S,
            const float* __restrict__ T, float* __restrict__ out) {
  __shared__ uint8_t lds[32768];      // 2 x (A 8K + B 8K) staging; then Xs
  __shared__ float mean_s[16], rstd_s[16];

  const int tid = threadIdx.x;
  const int w = tid >> 6;            // wave 0..3
  const int lane = tid & 63;
  const int q = lane >> 4;           // quad
  const int c = lane & 15;

  // ---- XCD banding: b&7 = XCD (round-robin dispatch), 12x24 rectangle ----
  const int b = blockIdx.x;
  const int xcd = b & 7;
  const int s_ = b >> 3;             // 0..287
  const int bx = (xcd >> 1) * 12 + (s_ % 12);
  const int by = (xcd & 1) * 24 + (s_ / 12);
  const int m0 = bx * 128, n0 = by * 128;

  f32x4 acc[4][4];
#pragma unroll
  for (int i = 0; i < 4; ++i)
#pragma unroll
    for (int j = 0; j < 4; ++j)
      acc[i][j] = (f32x4){0.f, 0.f, 0.f, 0.f};

  const int mbase = (w & 1) * 64;
  const int nbase = (w >> 1) * 64;

  // staging lane decomposition (BK=32: rows of 64 B, 4 lanes/row)
  const int srow = w * 32 + (lane >> 2);   // +16 for second instr
  const int sgrp = lane & 3;

  // chunk layout in LDS: base + row*64 + grp*16 ; A at +0, B at +8192
#define STAGE(kb_, base_)                                                     \
  do {                                                                        \
    gload_lds16(At + (size_t)(m0 + srow) * NN + (kb_) * 32 + sgrp * 8,        \
                (base_) + (w * 32) * 64);                                     \
    gload_lds16(At + (size_t)(m0 + srow + 16) * NN + (kb_) * 32 + sgrp * 8,   \
                (base_) + (w * 32 + 16) * 64);                                \
    gload_lds16(Bt + (size_t)(n0 + srow) * NN + (kb_) * 32 + sgrp * 8,        \
                (base_) + 8192 + (w * 32) * 64);                              \
    gload_lds16(Bt + (size_t)(n0 + srow + 16) * NN + (kb_) * 32 + sgrp * 8,   \
                (base_) + 8192 + (w * 32 + 16) * 64);                         \
  } while (0)

  // ---------------- GEMM1: 8 chunks of BK=32, double-buffered ----------------
  STAGE(0, lds);
#pragma unroll
  for (int kb = 0; kb < 8; ++kb) {
    uint8_t* cur = lds + (kb & 1) * 16384;
    uint8_t* nxt = lds + ((kb + 1) & 1) * 16384;
    __syncthreads();                 // staging of cur complete; prev compute done
    if (kb < 7) STAGE(kb + 1, nxt);  // in flight during this chunk's compute
    bf16x8 a[4], bfr[4];
#pragma unroll
    for (int t4 = 0; t4 < 4; ++t4) {
      a[t4]   = *(const bf16x8*)(cur + (mbase + t4 * 16 + c) * 64 + q * 16);
      bfr[t4] = *(const bf16x8*)(cur + 8192 + (nbase + t4 * 16 + c) * 64 + q * 16);
    }
#pragma unroll
    for (int ti = 0; ti < 4; ++ti)
#pragma unroll
      for (int tj = 0; tj < 4; ++tj)
        acc[ti][tj] = MFMA16(a[ti], bfr[tj], acc[ti][tj]);
  }
#undef STAGE

  // ------------- GEMM2 prefetch (L2-resident WB; hidden under barrier+scatter) -------------
  const int fb = w * 32;
  const __bf16* wb0 = WB + (fb + c) * 32 + q * 8;
  const __bf16* wb1 = WB + (fb + 16 + c) * 32 + q * 8;
  bf16x8 pb0[4], pb1[4];
#pragma unroll
  for (int p = 0; p < 4; ++p) {
    pb0[p] = *(const bf16x8*)(wb0 + p * 4096);
    pb1[p] = *(const bf16x8*)(wb1 + p * 4096);
  }

  __syncthreads();   // all staging/compute reads done; lds becomes Xs[16][1024]

  // ------------- LN stats (in-wave) + packed-b32 swizzled scatter -------------
  // Xs byte addr for element (row r, k): g=k>>3; G = g ^ (g>>4) ^ (r&7);
  // addr = r*2048 + G*16 + (k&7)*2
  const int i_hi = w & 1, l_hi = w >> 1;
#pragma unroll
  for (int ab = 0; ab < 2; ++ab) {
#pragma unroll
    for (int cb = 0; cb < 2; ++cb) {
      float s1 = 0.f, s2 = 0.f;
#pragma unroll
      for (int dti = 0; dti < 2; ++dti)
#pragma unroll
        for (int dtj = 0; dtj < 2; ++dtj)
#pragma unroll
          for (int reg = 0; reg < 4; ++reg) {
            const float v = acc[ab * 2 + dti][cb * 2 + dtj][reg];
            s1 += v; s2 += v * v;
          }
#pragma unroll
      for (int off = 32; off; off >>= 1) {
        s1 += __shfl_xor(s1, off);
        s2 += __shfl_xor(s2, off);
      }
      const float mean = s1 * (1.0f / 1024.0f);
      const float var = s2 * (1.0f / 1024.0f) - mean * mean;
      const float rstd = rsqrtf(var + 1e-5f);
      const int r = (i_hi * 2 + ab) * 4 + (l_hi * 2 + cb);
      if (lane == 0) { mean_s[r] = mean; rstd_s[r] = rstd; }
      const int r7 = r & 7;
#pragma unroll
      for (int dti = 0; dti < 2; ++dti)
#pragma unroll
        for (int dtj = 0; dtj < 2; ++dtj)
#pragma unroll
          for (int rp = 0; rp < 4; rp += 2) {
            const float x = acc[ab * 2 + dti][cb * 2 + dtj][rp];
            const float y = acc[ab * 2 + dti][cb * 2 + dtj][rp + 1];
            const float send = (c & 1) ? x : y;
            const float recv = __shfl_xor(send, 1);
            const float vlo = (c & 1) ? recv : x;
            const float vhi = (c & 1) ? y : recv;
            const int reg_w = (c & 1) ? rp + 1 : rp;
            const int j = dti * 16 + q * 4 + reg_w;
            const int mm0 = dtj * 16 + (c & ~1);
            const int k = j * 32 + mm0;
            const int g = k >> 3;
            const int G = g ^ (g >> 4) ^ r7;
            const uint32_t dw =
                ((uint32_t)bf16_bits(vhi) << 16) | (uint32_t)bf16_bits(vlo);
            *(uint32_t*)(lds + r * 2048 + G * 16 + (mm0 & 7) * 2) = dw;
          }
    }
  }

  __syncthreads();   // Xs + stats visible

  // ------------- GEMM2: Xs(16x1024) @ Wa^T -> 16x128, depth-4 pipeline -------------
  f32x4 acc2[2];
  acc2[0] = (f32x4){0.f, 0.f, 0.f, 0.f};
  acc2[1] = (f32x4){0.f, 0.f, 0.f, 0.f};
  const int c7 = c & 7;
#pragma unroll
  for (int kstep = 0; kstep < 32; ++kstep) {
    const int g = kstep * 4 + q;
    const int G = g ^ (g >> 4) ^ c7;
    const bf16x8 av = *(const bf16x8*)(lds + c * 2048 + G * 16);
    acc2[0] = MFMA16(av, pb0[kstep & 3], acc2[0]);
    acc2[1] = MFMA16(av, pb1[kstep & 3], acc2[1]);
    if (kstep < 28) {
      pb0[kstep & 3] = *(const bf16x8*)(wb0 + (kstep + 4) * 4096);
      pb1[kstep & 3] = *(const bf16x8*)(wb1 + (kstep + 4) * 4096);
    }
  }

  // ------------- epilogue: affine + store -------------
  const float S0 = S[fb + c], T0 = T[fb + c];
  const float S1 = S[fb + 16 + c], T1 = T[fb + 16 + c];
#pragma unroll
  for (int reg = 0; reg < 4; ++reg) {
    const int r = q * 4 + reg;             // LN row 0..15
    const float mean = mean_s[r], rstd = rstd_s[r];
    const int i = bx * 4 + (r >> 2);
    const int l = by * 4 + (r & 3);
    const size_t base = ((size_t)i * LL + l) * FF;
    out[base + fb + c]      = rstd * (acc2[0][reg] - mean * S0) + T0;
    out[base + fb + 16 + c] = rstd * (acc2[1][reg] - mean * S1) + T1;
  }
}

// ---------------------------------------------------------------------------
extern "C" void kernel_launch(void* const* d_in, const int* in_sizes, int n_in,
                              void* d_out, int out_size, void* d_ws, size_t ws_size,
                              hipStream_t stream) {
  const float* x_down   = (const float*)d_in[0];
  const float* x_down_w = (const float*)d_in[1];
  const float* a2       = (const float*)d_in[2];
  const float* b2       = (const float*)d_in[3];
  const float* W        = (const float*)d_in[4];
  const float* bias     = (const float*)d_in[5];
  float* out = (float*)d_out;

  uint8_t* ws = (uint8_t*)d_ws;
  __bf16* At  = (__bf16*)(ws);                 // 6144*256*2 = 3145728 B
  __bf16* Bt  = (__bf16*)(ws + 3145728);       // 3145728 B
  __bf16* WB  = (__bf16*)(ws + 6291456);       // 128*1024*2 = 262144 B
  float*  S   = (float*)(ws + 6553600);        // 512 B
  float*  T   = (float*)(ws + 6554112);        // 512 B

  prep_all<<<dim3(3200), dim3(256), 0, stream>>>(x_down, x_down_w, W, a2, b2,
                                                 bias, At, Bt, WB, S, T);
  fused5<<<dim3(2304), dim3(256), 0, stream>>>(At, Bt, WB, S, T, out);
}

// Round 6
// 133.255 us; speedup vs baseline: 1.0698x; 1.0698x over previous
//
#include <hip/hip_runtime.h>
#include <hip/hip_bf16.h>
#include <stdint.h>

// Problem constants (B=1)
#define NN   256     // MSA depth (contraction K of GEMM1)
#define LL   192
#define MDIM 6144    // L*J
#define D2   1024    // J*J
#define FF   128     // n_feat_out

typedef __bf16 bf16x8 __attribute__((ext_vector_type(8)));
typedef float  f32x4  __attribute__((ext_vector_type(4)));

#define MFMA16(a, b, c) __builtin_amdgcn_mfma_f32_16x16x32_bf16(a, b, c, 0, 0, 0)

__device__ __forceinline__ void gload_lds16(const void* g, void* l) {
  __builtin_amdgcn_global_load_lds(
      (__attribute__((address_space(1))) void*)(g),
      (__attribute__((address_space(3))) void*)(l),
      16, 0, 0);
}

static __device__ __forceinline__ unsigned short bf16_bits(float v) {
  __bf16 h = (__bf16)v;
  return __builtin_bit_cast(unsigned short, h);
}

// ---------------------------------------------------------------------------
// Unified prep (one launch):
//  blocks [0,1536):    transpose x_down  [256][6144] f32 -> At [6144][256] bf16
//  blocks [1536,3072): transpose x_down_w            -> Bt
//  blocks [3072,3200): WB[fragment-linear] = bf16(a2*W), S = colsum, T = b2@W+b
// ---------------------------------------------------------------------------
__global__ __launch_bounds__(256)
void prep_all(const float* __restrict__ x1, const float* __restrict__ x2,
              const float* __restrict__ W, const float* __restrict__ a2,
              const float* __restrict__ b2, const float* __restrict__ bias,
              __bf16* __restrict__ At, __bf16* __restrict__ Bt,
              __bf16* __restrict__ WB, float* __restrict__ S,
              float* __restrict__ T) {
  __shared__ float tile[32][33];
  const int b = blockIdx.x;
  const int t = threadIdx.x;
  if (b < 3072) {
    const float* src = (b < 1536) ? x1 : x2;
    __bf16* dst = (b < 1536) ? At : Bt;
    const int bb = (b < 1536) ? b : b - 1536;
    const int m0 = (bb % 192) * 32;
    const int k0 = (bb / 192) * 32;
    {
      const int kr = t >> 3, mc = (t & 7) * 4;
      const float4 v = *(const float4*)&src[(size_t)(k0 + kr) * MDIM + m0 + mc];
      tile[kr][mc + 0] = v.x;
      tile[kr][mc + 1] = v.y;
      tile[kr][mc + 2] = v.z;
      tile[kr][mc + 3] = v.w;
    }
    __syncthreads();
    {
      const int mr = t >> 3, kc = (t & 7) * 4;
      ushort4 u;
      u.x = bf16_bits(tile[kc + 0][mr]);
      u.y = bf16_bits(tile[kc + 1][mr]);
      u.z = bf16_bits(tile[kc + 2][mr]);
      u.w = bf16_bits(tile[kc + 3][mr]);
      *(ushort4*)&dst[(size_t)(m0 + mr) * NN + k0 + kc] = u;
    }
  } else {
    const int f = b - 3072;
    float s = 0.f, tt = 0.f;
#pragma unroll
    for (int it = 0; it < 4; ++it) {
      const int k = t + it * 256;
      const float wv = W[(size_t)k * FF + f];
      const __bf16 wa = (__bf16)(a2[k] * wv);
      WB[(size_t)(k >> 5) * 4096 + f * 32 + ((k >> 3) & 3) * 8 + (k & 7)] = wa;
      s += (float)wa;
      tt += b2[k] * wv;
    }
#pragma unroll
    for (int off = 32; off; off >>= 1) {
      s += __shfl_xor(s, off);
      tt += __shfl_xor(tt, off);
    }
    const int wv_ = t >> 6, ln = t & 63;
    if (ln == 0) { tile[0][wv_] = s; tile[1][wv_] = tt; }
    __syncthreads();
    if (t == 0) {
      S[f] = tile[0][0] + tile[0][1] + tile[0][2] + tile[0][3];
      T[f] = tile[1][0] + tile[1][1] + tile[1][2] + tile[1][3] + bias[f];
    }
  }
}

// ---------------------------------------------------------------------------
// Fused kernel R6 = R4 structure (proven 70.4us) + occupancy push:
//   __launch_bounds__(256,4) -> 128 unified regs/thread -> 4 blocks/CU.
//   Register phase budget: GEMM1 acc64(AGPR)+frags32+addr~15;
//   scatter acc64+WB-prefetch(depth2)16+temps; GEMM2 acc2 8+pipe16.
//   Spill tripwire: WRITE_SIZE must stay exactly 18432 KB.
// XCD banding: b&7 = XCD, 12x24 tile rectangle -> per-XCD L2 set ~2.6MB.
// GEMM1: 128x128, K=256, BK=64 single-buffer global_load_lds staging with
// 128B-row XOR swizzle (verified ~free conflicts). Then per-32x32-block LN
// stats, packed-b32 swizzled Xs scatter, GEMM2 (WB frag-linear, depth-2
// register pipeline), affine epilogue. out = rstd*(x@Wa - mean*S) + T.
// ---------------------------------------------------------------------------
__global__ __launch_bounds__(256, 4)
void fused6(const __bf16* __restrict__ At, const __bf16* __restrict__ Bt,
            const __bf16* __restrict__ WB, const float* __restrict__ S,
            const float* __restrict__ T, float* __restrict__ out) {
  __shared__ uint8_t lds[32768];      // GEMM1 stage (16K A + 16K B), then Xs
  __shared__ float mean_s[16], rstd_s[16];

  const int tid = threadIdx.x;
  const int w = tid >> 6;            // wave 0..3
  const int lane = tid & 63;
  const int q = lane >> 4;           // quad
  const int c = lane & 15;

  // ---- XCD banding: b&7 = XCD (round-robin dispatch), 12x24 rectangle ----
  const int b = blockIdx.x;
  const int xcd = b & 7;
  const int s_ = b >> 3;             // 0..287
  const int bx = (xcd >> 1) * 12 + (s_ % 12);
  const int by = (xcd & 1) * 24 + (s_ / 12);
  const int m0 = bx * 128, n0 = by * 128;

  uint8_t* As = lds;
  uint8_t* Bs = lds + 16384;

  // staging lane decomposition: 8 lanes per 128B row (BK=64 bf16)
  const int l8 = lane & 7;
  const int r8 = lane >> 3;
  const int gsw = l8 ^ r8;           // XOR-swizzled source 16B-group

  f32x4 acc[4][4];
#pragma unroll
  for (int i = 0; i < 4; ++i)
#pragma unroll
    for (int j = 0; j < 4; ++j)
      acc[i][j] = (f32x4){0.f, 0.f, 0.f, 0.f};

  const int mbase = (w & 1) * 64;
  const int nbase = (w >> 1) * 64;

  // ---------------- GEMM1 K-loop: 4 chunks of BK=64 ----------------
  for (int kb = 0; kb < 4; ++kb) {
    __syncthreads();
#pragma unroll
    for (int s4 = 0; s4 < 4; ++s4) {
      const int mrow = s4 * 32 + w * 8 + r8;   // 0..127, disjoint per wave
      const uint8_t* ga = (const uint8_t*)At +
          (((size_t)(m0 + mrow)) * NN + kb * 64 + gsw * 8) * 2;
      const uint8_t* gb = (const uint8_t*)Bt +
          (((size_t)(n0 + mrow)) * NN + kb * 64 + gsw * 8) * 2;
      gload_lds16(ga, As + (s4 * 32 + w * 8) * 128);
      gload_lds16(gb, Bs + (s4 * 32 + w * 8) * 128);
    }
    __syncthreads();
#pragma unroll
    for (int ks = 0; ks < 2; ++ks) {
      bf16x8 a[4], bfr[4];
#pragma unroll
      for (int t4 = 0; t4 < 4; ++t4) {
        const int mr = mbase + t4 * 16 + c;
        const int slot = (ks * 4 + q) ^ (lane & 7);
        a[t4] = *(const bf16x8*)(As + mr * 128 + slot * 16);
        const int nr = nbase + t4 * 16 + c;
        bfr[t4] = *(const bf16x8*)(Bs + nr * 128 + slot * 16);
      }
#pragma unroll
      for (int ti = 0; ti < 4; ++ti)
#pragma unroll
        for (int tj = 0; tj < 4; ++tj)
          acc[ti][tj] = MFMA16(a[ti], bfr[tj], acc[ti][tj]);
    }
  }

  // ------------- GEMM2 depth-2 prefetch (L2-resident WB; hidden under scatter) -------------
  const int fb = w * 32;
  const __bf16* wb0 = WB + (fb + c) * 32 + q * 8;
  const __bf16* wb1 = WB + (fb + 16 + c) * 32 + q * 8;
  bf16x8 pb0[2], pb1[2];
#pragma unroll
  for (int p = 0; p < 2; ++p) {
    pb0[p] = *(const bf16x8*)(wb0 + p * 4096);
    pb1[p] = *(const bf16x8*)(wb1 + p * 4096);
  }

  __syncthreads();   // all staging ds_reads done; lds becomes Xs[16][1024]

  // ------------- LN stats (in-wave) + packed-b32 swizzled scatter -------------
  // Xs byte addr for element (row r, k): g=k>>3; G = g ^ (g>>4) ^ (r&7);
  // addr = r*2048 + G*16 + (k&7)*2
  const int i_hi = w & 1, l_hi = w >> 1;
#pragma unroll
  for (int ab = 0; ab < 2; ++ab) {
#pragma unroll
    for (int cb = 0; cb < 2; ++cb) {
      float s1 = 0.f, s2 = 0.f;
#pragma unroll
      for (int dti = 0; dti < 2; ++dti)
#pragma unroll
        for (int dtj = 0; dtj < 2; ++dtj)
#pragma unroll
          for (int reg = 0; reg < 4; ++reg) {
            const float v = acc[ab * 2 + dti][cb * 2 + dtj][reg];
            s1 += v; s2 += v * v;
          }
#pragma unroll
      for (int off = 32; off; off >>= 1) {
        s1 += __shfl_xor(s1, off);
        s2 += __shfl_xor(s2, off);
      }
      const float mean = s1 * (1.0f / 1024.0f);
      const float var = s2 * (1.0f / 1024.0f) - mean * mean;
      const float rstd = rsqrtf(var + 1e-5f);
      const int r = (i_hi * 2 + ab) * 4 + (l_hi * 2 + cb);
      if (lane == 0) { mean_s[r] = mean; rstd_s[r] = rstd; }
      const int r7 = r & 7;
#pragma unroll
      for (int dti = 0; dti < 2; ++dti)
#pragma unroll
        for (int dtj = 0; dtj < 2; ++dtj)
#pragma unroll
          for (int rp = 0; rp < 4; rp += 2) {
            const float x = acc[ab * 2 + dti][cb * 2 + dtj][rp];
            const float y = acc[ab * 2 + dti][cb * 2 + dtj][rp + 1];
            const float send = (c & 1) ? x : y;
            const float recv = __shfl_xor(send, 1);
            const float vlo = (c & 1) ? recv : x;
            const float vhi = (c & 1) ? y : recv;
            const int reg_w = (c & 1) ? rp + 1 : rp;
            const int j = dti * 16 + q * 4 + reg_w;
            const int mm0 = dtj * 16 + (c & ~1);
            const int k = j * 32 + mm0;
            const int g = k >> 3;
            const int G = g ^ (g >> 4) ^ r7;
            const uint32_t dw =
                ((uint32_t)bf16_bits(vhi) << 16) | (uint32_t)bf16_bits(vlo);
            *(uint32_t*)(lds + r * 2048 + G * 16 + (mm0 & 7) * 2) = dw;
          }
    }
  }

  __syncthreads();   // Xs + stats visible

  // ------------- GEMM2: Xs(16x1024) @ Wa^T -> 16x128, depth-2 pipeline -------------
  f32x4 acc2[2];
  acc2[0] = (f32x4){0.f, 0.f, 0.f, 0.f};
  acc2[1] = (f32x4){0.f, 0.f, 0.f, 0.f};
  const int c7 = c & 7;
#pragma unroll
  for (int kstep = 0; kstep < 32; ++kstep) {
    const int g = kstep * 4 + q;
    const int G = g ^ (g >> 4) ^ c7;
    const bf16x8 av = *(const bf16x8*)(lds + c * 2048 + G * 16);
    acc2[0] = MFMA16(av, pb0[kstep & 1], acc2[0]);
    acc2[1] = MFMA16(av, pb1[kstep & 1], acc2[1]);
    if (kstep < 30) {
      pb0[kstep & 1] = *(const bf16x8*)(wb0 + (kstep + 2) * 4096);
      pb1[kstep & 1] = *(const bf16x8*)(wb1 + (kstep + 2) * 4096);
    }
  }

  // ------------- epilogue: affine + store -------------
  const float S0 = S[fb + c], T0 = T[fb + c];
  const float S1 = S[fb + 16 + c], T1 = T[fb + 16 + c];
#pragma unroll
  for (int reg = 0; reg < 4; ++reg) {
    const int r = q * 4 + reg;             // LN row 0..15
    const float mean = mean_s[r], rstd = rstd_s[r];
    const int i = bx * 4 + (r >> 2);
    const int l = by * 4 + (r & 3);
    const size_t base = ((size_t)i * LL + l) * FF;
    out[base + fb + c]      = rstd * (acc2[0][reg] - mean * S0) + T0;
    out[base + fb + 16 + c] = rstd * (acc2[1][reg] - mean * S1) + T1;
  }
}

// ---------------------------------------------------------------------------
extern "C" void kernel_launch(void* const* d_in, const int* in_sizes, int n_in,
                              void* d_out, int out_size, void* d_ws, size_t ws_size,
                              hipStream_t stream) {
  const float* x_down   = (const float*)d_in[0];
  const float* x_down_w = (const float*)d_in[1];
  const float* a2       = (const float*)d_in[2];
  const float* b2       = (const float*)d_in[3];
  const float* W        = (const float*)d_in[4];
  const float* bias     = (const float*)d_in[5];
  float* out = (float*)d_out;

  uint8_t* ws = (uint8_t*)d_ws;
  __bf16* At  = (__bf16*)(ws);                 // 6144*256*2 = 3145728 B
  __bf16* Bt  = (__bf16*)(ws + 3145728);       // 3145728 B
  __bf16* WB  = (__bf16*)(ws + 6291456);       // 128*1024*2 = 262144 B
  float*  S   = (float*)(ws + 6553600);        // 512 B
  float*  T   = (float*)(ws + 6554112);        // 512 B

  prep_all<<<dim3(3200), dim3(256), 0, stream>>>(x_down, x_down_w, W, a2, b2,
                                                 bias, At, Bt, WB, S, T);
  fused6<<<dim3(2304), dim3(256), 0, stream>>>(At, Bt, WB, S, T, out);
}